// Round 10
// baseline (549.657 us; speedup 1.0000x reference)
//
#include <hip/hip_runtime.h>

#define N_ROWS 65536
#define D 256
#define K 1024
#define DECAYF 0.99f
#define OMDF 0.01f
#define EPSF 1e-5f

typedef _Float16 f16;
typedef _Float16 f16x8 __attribute__((ext_vector_type(8)));
typedef float f32x16 __attribute__((ext_vector_type(16)));
typedef float f32x4 __attribute__((ext_vector_type(4)));

// ---------------- fused prep: zero dw/counts + codebook norms + hi/lo split ----------------
// wsB granule g (16B), g = stuff*64 + lane:
//   lane = h*32+l31 ; stuff = ((((ct*4+dk)*4+ks)*2+v)*8 + cfg)
//   content: fp16 (v=0 hi, v=1 lo) of cb[ct*256+cfg*32+l31][dk*64+ks*16+h*8 + e], e=0..7
__global__ __launch_bounds__(256) void prep_kernel(const float* __restrict__ cb,
                                                   float* __restrict__ cnorm,
                                                   char* __restrict__ wsB,
                                                   float* __restrict__ dw,
                                                   float* __restrict__ counts) {
    const int tid = threadIdx.x;
    const int bid = blockIdx.x;
    const int g = bid * 256 + tid;          // 0..65535
    *reinterpret_cast<float4*>(dw + (size_t)g * 4) = make_float4(0.f, 0.f, 0.f, 0.f);
    if (g < K) counts[g] = 0.f;
    {
        const int row = bid * 4 + (tid >> 6);
        const int lane = tid & 63;
        const float4 v = *reinterpret_cast<const float4*>(cb + (size_t)row * D + lane * 4);
        float s = v.x * v.x + v.y * v.y + v.z * v.z + v.w * v.w;
        #pragma unroll
        for (int m = 32; m; m >>= 1) s += __shfl_xor(s, m);
        if (lane == 0) cnorm[row] = s;
    }
    {
        const int l31 = g & 31;
        const int h   = (g >> 5) & 1;
        const int cfg = (g >> 6) & 7;
        const int v   = (g >> 9) & 1;
        const int ks  = (g >> 10) & 3;
        const int dk  = (g >> 12) & 3;
        const int ct  = (g >> 14) & 3;
        const int code = ct * 256 + cfg * 32 + l31;
        const int dim0 = dk * 64 + ks * 16 + h * 8;
        const float* src = cb + (size_t)code * D + dim0;
        f16 out[8];
        #pragma unroll
        for (int e = 0; e < 8; ++e) {
            const float f = src[e];
            const f16 hi = (f16)f;
            out[e] = v ? (f16)(f - (float)hi) : hi;
        }
        *reinterpret_cast<f16x8*>(wsB + (size_t)g * 16) = *reinterpret_cast<f16x8*>(out);
    }
}

// ---------------- MFMA argmin v4: 256-row tile, LDS-staged A+B, per-ct LDS argmin merge ----------------
// 512 thr = 8 waves: rw = wave>>2 (2 row-waves x 128 rows), cw = wave&3 (4 col-waves x 64 codes/ct)
// wave tile per ct: 128 rows (rf=4) x 64 codes (cf=2); phases: 4 ct x 8 dk2 (32-dim chunks)
__global__ __launch_bounds__(512, 2) void argmin_mfma_kernel(
        const float* __restrict__ x, const char* __restrict__ wsB,
        const float* __restrict__ cnorm, int* __restrict__ idx_out,
        float* __restrict__ counts) {
    __shared__ char smem[73728];   // A: 32KB @0 | B: 32KB @32768 | Sv 4KB @65536 | Si 4KB @69632
    char* Alds = smem;
    char* Blds = smem + 32768;
    float* Sv = reinterpret_cast<float*>(smem + 65536);   // [4 cw][256 rows]
    int*   Si = reinterpret_cast<int*>(smem + 69632);
    const int tid = threadIdx.x;
    const int wave = tid >> 6;
    const int lane = tid & 63;
    const int l31 = lane & 31;
    const int h = lane >> 5;
    const int rw = wave >> 2;
    const int cw = wave & 3;
    const int n0 = blockIdx.x * 256;

    // init merge buffers
    Sv[tid] = 3.4e38f; Sv[tid + 512] = 3.4e38f;
    Si[tid] = 0; Si[tid + 512] = 0;

    // staging decode for A: 16 floats per thread
    const int s_row = tid >> 1;          // 0..255
    const int c16 = tid & 1;             // 16-dim half of the 32-dim chunk
    const int ssw = s_row & 7;
    char* s_rowbase = Alds + s_row * 128;

    // compute-side A addressing
    const int arow[4] = { rw * 128 + l31, rw * 128 + 32 + l31,
                          rw * 128 + 64 + l31, rw * 128 + 96 + l31 };

    #pragma unroll 1
    for (int ct = 0; ct < 4; ++ct) {
        f32x16 acc[4][2];
        #pragma unroll
        for (int rf = 0; rf < 4; ++rf)
            #pragma unroll
            for (int cf = 0; cf < 2; ++cf)
                #pragma unroll
                for (int r = 0; r < 16; ++r) acc[rf][cf][r] = 0.f;

        #pragma unroll 1
        for (int p = 0; p < 8; ++p) {
            const int dk2 = (ct & 1) ? (7 - p) : p;   // serpentine: reuse A at ct boundary
            __syncthreads();
            if (!(ct > 0 && p == 0)) {
                // stage A chunk: 256 rows x 32 dims -> hi/lo fp16, swizzled granules
                const f32x4* src = reinterpret_cast<const f32x4*>(
                    x + (size_t)(n0 + s_row) * D + dk2 * 32 + c16 * 16);
                const f32x4 a0 = __builtin_nontemporal_load(src + 0);
                const f32x4 a1 = __builtin_nontemporal_load(src + 1);
                const f32x4 a2 = __builtin_nontemporal_load(src + 2);
                const f32x4 a3 = __builtin_nontemporal_load(src + 3);
                float f[16] = {a0[0],a0[1],a0[2],a0[3], a1[0],a1[1],a1[2],a1[3],
                               a2[0],a2[1],a2[2],a2[3], a3[0],a3[1],a3[2],a3[3]};
                f16 hi8[16], lo8[16];
                #pragma unroll
                for (int e = 0; e < 16; ++e) {
                    hi8[e] = (f16)f[e];
                    lo8[e] = (f16)(f[e] - (float)hi8[e]);
                }
                #pragma unroll
                for (int hp = 0; hp < 2; ++hp) {
                    const int ghi = (c16 * 2 + hp) ^ ssw;        // v=0
                    const int glo = (4 + c16 * 2 + hp) ^ ssw;    // v=1
                    *reinterpret_cast<f16x8*>(s_rowbase + ghi * 16) = *reinterpret_cast<f16x8*>(&hi8[hp * 8]);
                    *reinterpret_cast<f16x8*>(s_rowbase + glo * 16) = *reinterpret_cast<f16x8*>(&lo8[hp * 8]);
                }
            }
            // stage B tile: 32KB linear burst from pre-swizzled wsB
            {
                const int4* gsrc = reinterpret_cast<const int4*>(wsB + (size_t)(ct * 8 + dk2) * 32768);
                int4* ldst = reinterpret_cast<int4*>(Blds);
                #pragma unroll
                for (int i = 0; i < 4; ++i) ldst[tid + i * 512] = gsrc[tid + i * 512];
            }
            __syncthreads();
            // compute: 2 k-steps x 24 MFMA
            #pragma unroll
            for (int ks2 = 0; ks2 < 2; ++ks2) {
                const int g = ks2 * 2 + h;
                f16x8 Ah[4], Al[4];
                #pragma unroll
                for (int rf = 0; rf < 4; ++rf) {
                    char* ab = Alds + arow[rf] * 128;
                    const int asw = arow[rf] & 7;
                    Ah[rf] = *reinterpret_cast<const f16x8*>(ab + ((g ^ asw) * 16));
                    Al[rf] = *reinterpret_cast<const f16x8*>(ab + (((4 + g) ^ asw) * 16));
                }
                #pragma unroll
                for (int cf = 0; cf < 2; ++cf) {
                    const int cfg = cw * 2 + cf;
                    const f16x8 Bh = *reinterpret_cast<const f16x8*>(Blds + (ks2 * 16 + cfg) * 1024 + lane * 16);
                    const f16x8 Bl = *reinterpret_cast<const f16x8*>(Blds + (ks2 * 16 + 8 + cfg) * 1024 + lane * 16);
                    #pragma unroll
                    for (int rf = 0; rf < 4; ++rf) {
                        acc[rf][cf] = __builtin_amdgcn_mfma_f32_32x32x16_f16(Ah[rf], Bh, acc[rf][cf], 0, 0, 0);
                        acc[rf][cf] = __builtin_amdgcn_mfma_f32_32x32x16_f16(Ah[rf], Bl, acc[rf][cf], 0, 0, 0);
                        acc[rf][cf] = __builtin_amdgcn_mfma_f32_32x32x16_f16(Al[rf], Bh, acc[rf][cf], 0, 0, 0);
                    }
                }
            }
        }
        // fold this ct: per-row argmin over this wave's 64 codes, then merge into LDS
        const int codebase = ct * 256 + cw * 64;
        const float cn0 = cnorm[codebase + l31];
        const float cn1 = cnorm[codebase + 32 + l31];
        #pragma unroll
        for (int rf = 0; rf < 4; ++rf) {
            #pragma unroll
            for (int r = 0; r < 16; ++r) {
                const float d0 = cn0 - 2.f * acc[rf][0][r];
                const float d1 = cn1 - 2.f * acc[rf][1][r];
                float v = d0; int b = codebase + l31;
                if (d1 < v) { v = d1; b = codebase + 32 + l31; }
                #pragma unroll
                for (int m = 16; m; m >>= 1) {
                    const float ov = __shfl_xor(v, m);
                    const int ob = __shfl_xor(b, m);
                    if (ov < v || (ov == v && ob < b)) { v = ov; b = ob; }
                }
                if (l31 == 0) {
                    const int row = rw * 128 + rf * 32 + (r & 3) + 8 * (r >> 2) + 4 * h;
                    const int slot = cw * 256 + row;
                    const float pv = Sv[slot]; const int pb = Si[slot];
                    if (v < pv || (v == pv && b < pb)) { Sv[slot] = v; Si[slot] = b; }
                }
            }
        }
    }
    __syncthreads();
    if (tid < 256) {
        float v = Sv[tid];
        int b = Si[tid];
        #pragma unroll
        for (int w = 1; w < 4; ++w) {
            const float ov = Sv[w * 256 + tid];
            const int ob = Si[w * 256 + tid];
            if (ov < v || (ov == v && ob < b)) { v = ov; b = ob; }
        }
        idx_out[n0 + tid] = b;
        atomicAdd(&counts[b], 1.0f);
    }
}

// ---------------- quantized gather (nontemporal stores) ----------------
__global__ __launch_bounds__(256) void quant_kernel(const float* __restrict__ cb,
                                                    const int* __restrict__ idx,
                                                    float* __restrict__ quant) {
    const int n = blockIdx.x * 4 + (threadIdx.x >> 6);
    const int lane = threadIdx.x & 63;
    const int i = idx[n];
    const f32x4 c = *reinterpret_cast<const f32x4*>(cb + (size_t)i * D + lane * 4);
    __builtin_nontemporal_store(c, reinterpret_cast<f32x4*>(quant + (size_t)n * D + lane * 4));
}

// ---------------- one-hot encodings (nontemporal stores) ----------------
__global__ __launch_bounds__(256) void enc_kernel(const int* __restrict__ idx,
                                                  float* __restrict__ enc) {
    const int total = N_ROWS * (K / 4);
    for (int g = blockIdx.x * blockDim.x + threadIdx.x; g < total;
         g += gridDim.x * blockDim.x) {
        const int n = g >> 8;
        const int k0 = (g & 255) * 4;
        const int i = idx[n];
        f32x4 v;
        v[0] = (k0 == i) ? 1.f : 0.f;
        v[1] = (k0 + 1 == i) ? 1.f : 0.f;
        v[2] = (k0 + 2 == i) ? 1.f : 0.f;
        v[3] = (k0 + 3 == i) ? 1.f : 0.f;
        __builtin_nontemporal_store(v, reinterpret_cast<f32x4*>(enc + (size_t)g * 4));
    }
}

// ---------------- cs EMA + Laplace + exclusive scan (wave-scan) ----------------
__global__ __launch_bounds__(1024) void cs_scan_kernel(const float* __restrict__ ema_cs,
                                                       const float* __restrict__ counts,
                                                       float* __restrict__ cs_out,
                                                       int* __restrict__ cursor) {
    __shared__ float wsum[16];
    __shared__ int wisum[16];
    __shared__ float n_sh;
    const int k = threadIdx.x;
    const int wid = k >> 6;
    const int lane = k & 63;
    const float cnt = counts[k];
    const float c = ema_cs[k] * DECAYF + OMDF * cnt;
    const int ic = (int)cnt;
    int v = ic;
    #pragma unroll
    for (int d = 1; d < 64; d <<= 1) {
        const int t = __shfl_up(v, d);
        if (lane >= d) v += t;
    }
    float s = c;
    #pragma unroll
    for (int m = 32; m; m >>= 1) s += __shfl_xor(s, m);
    if (lane == 63) wisum[wid] = v;
    if (lane == 0) wsum[wid] = s;
    __syncthreads();
    if (k == 0) {
        float n = 0.f;
        for (int w = 0; w < 16; ++w) n += wsum[w];
        n_sh = n;
    }
    if (wid == 0 && lane < 16) {
        int wv = wisum[lane];
        #pragma unroll
        for (int d = 1; d < 16; d <<= 1) {
            const int t = __shfl_up(wv, d);
            if (lane >= d) wv += t;
        }
        wisum[lane] = wv;
    }
    __syncthreads();
    const float n = n_sh;
    cs_out[k] = (c + EPSF) / (n + c * EPSF) * n;
    const int wbase = (wid == 0) ? 0 : wisum[wid - 1];
    cursor[k] = wbase + v - ic;
}

// ---------------- scatter rows by code, block-aggregated ----------------
__global__ __launch_bounds__(256) void scatter_kernel(const int* __restrict__ idx,
                                                      int* __restrict__ cursor,
                                                      int* __restrict__ rowlist,
                                                      int* __restrict__ codelist) {
    __shared__ int hist[1024];
    const int tid = threadIdx.x;
    #pragma unroll
    for (int j = 0; j < 4; ++j) hist[tid + j * 256] = 0;
    __syncthreads();
    const int n = blockIdx.x * 256 + tid;
    const int i = idx[n];
    atomicAdd(&hist[i], 1);
    __syncthreads();
    #pragma unroll
    for (int j = 0; j < 4; ++j) {
        const int k = tid + j * 256;
        const int c = hist[k];
        hist[k] = (c > 0) ? atomicAdd(&cursor[k], c) : 0;
    }
    __syncthreads();
    const int pos = atomicAdd(&hist[i], 1);
    rowlist[pos] = n;
    codelist[pos] = i;
}

// ---------------- balanced segmented sum over sorted rowlist ----------------
__global__ __launch_bounds__(256) void chunk_sum_kernel(const float* __restrict__ x,
                                                        const int* __restrict__ rowlist,
                                                        const int* __restrict__ codelist,
                                                        float* __restrict__ dw) {
    const int wave = threadIdx.x >> 6;
    const int lane = threadIdx.x & 63;
    const int p0 = blockIdx.x * 32 + wave * 8;
    int rows[8], codes[8];
    #pragma unroll
    for (int j = 0; j < 8; ++j) {
        rows[j] = rowlist[p0 + j];
        codes[j] = codelist[p0 + j];
    }
    f32x4 v[8];
    #pragma unroll
    for (int j = 0; j < 8; ++j)
        v[j] = __builtin_nontemporal_load(
            reinterpret_cast<const f32x4*>(x + (size_t)rows[j] * D + lane * 4));
    f32x4 s = v[0];
    int cur = codes[0];
    #pragma unroll
    for (int j = 1; j < 8; ++j) {
        if (codes[j] != cur) {
            float* dst = dw + (size_t)cur * D + lane * 4;
            atomicAdd(dst + 0, s[0]); atomicAdd(dst + 1, s[1]);
            atomicAdd(dst + 2, s[2]); atomicAdd(dst + 3, s[3]);
            cur = codes[j];
            s = v[j];
        } else {
            s[0] += v[j][0]; s[1] += v[j][1]; s[2] += v[j][2]; s[3] += v[j][3];
        }
    }
    float* dst = dw + (size_t)cur * D + lane * 4;
    atomicAdd(dst + 0, s[0]); atomicAdd(dst + 1, s[1]);
    atomicAdd(dst + 2, s[2]); atomicAdd(dst + 3, s[3]);
}

// ---------------- ema_w + new codebook ----------------
__global__ __launch_bounds__(256) void ema_kernel(const float* __restrict__ ema_w,
                                                  const float* __restrict__ dw,
                                                  const float* __restrict__ cs,
                                                  float* __restrict__ w_out,
                                                  float* __restrict__ cb_out) {
    const int e4 = blockIdx.x * blockDim.x + threadIdx.x;
    const int k = e4 >> 6;
    const float csk = cs[k];
    const float4 w = *reinterpret_cast<const float4*>(ema_w + (size_t)e4 * 4);
    const float4 d = *reinterpret_cast<const float4*>(dw + (size_t)e4 * 4);
    float4 nw, nc;
    nw.x = w.x * DECAYF + OMDF * d.x;
    nw.y = w.y * DECAYF + OMDF * d.y;
    nw.z = w.z * DECAYF + OMDF * d.z;
    nw.w = w.w * DECAYF + OMDF * d.w;
    nc.x = nw.x / csk; nc.y = nw.y / csk; nc.z = nw.z / csk; nc.w = nw.w / csk;
    *reinterpret_cast<float4*>(w_out + (size_t)e4 * 4) = nw;
    *reinterpret_cast<float4*>(cb_out + (size_t)e4 * 4) = nc;
}

extern "C" void kernel_launch(void* const* d_in, const int* in_sizes, int n_in,
                              void* d_out, int out_size, void* d_ws, size_t ws_size,
                              hipStream_t stream) {
    (void)in_sizes; (void)n_in; (void)out_size; (void)ws_size;
    const float* x      = (const float*)d_in[0];
    const float* cb     = (const float*)d_in[1];
    const float* ema_w  = (const float*)d_in[2];
    const float* ema_cs = (const float*)d_in[3];

    float* out    = (float*)d_out;
    float* quant  = out;
    float* enc    = quant + 16777216;
    float* cs_out = enc + 67108864;
    float* w_out  = cs_out + 1024;
    float* cb_out = w_out + 262144;

    float* ws       = (float*)d_ws;
    float* counts   = ws;                          // 1024 f
    float* dw       = ws + 1024;                   // 262144 f
    float* cnorm    = ws + 263168;                 // 1024 f
    int*   cursor   = (int*)(ws + 264192);         // 1024 i
    int*   idx      = (int*)(ws + 265216);         // 65536 i
    int*   rowlist  = (int*)(ws + 330752);         // 65536 i
    int*   codelist = (int*)(ws + 396288);         // 65536 i
    char*  wsB      = (char*)(ws + 461824);        // 1 MiB, 16B aligned

    prep_kernel<<<256, 256, 0, stream>>>(cb, cnorm, wsB, dw, counts);
    argmin_mfma_kernel<<<N_ROWS / 256, 512, 0, stream>>>(x, wsB, cnorm, idx, counts);
    quant_kernel<<<N_ROWS / 4, 256, 0, stream>>>(cb, idx, quant);
    enc_kernel<<<2048, 256, 0, stream>>>(idx, enc);
    cs_scan_kernel<<<1, 1024, 0, stream>>>(ema_cs, counts, cs_out, cursor);
    scatter_kernel<<<N_ROWS / 256, 256, 0, stream>>>(idx, cursor, rowlist, codelist);
    chunk_sum_kernel<<<2048, 256, 0, stream>>>(x, rowlist, codelist, dw);
    ema_kernel<<<65536 / 256, 256, 0, stream>>>(ema_w, dw, cs_out, w_out, cb_out);
}

// Round 11
// 357.292 us; speedup vs baseline: 1.5384x; 1.5384x over previous
//
#include <hip/hip_runtime.h>

#define N_ROWS 65536
#define D 256
#define K 1024
#define DECAYF 0.99f
#define OMDF 0.01f
#define EPSF 1e-5f
#define MARGIN 0.5f

typedef _Float16 f16;
typedef _Float16 f16x8 __attribute__((ext_vector_type(8)));
typedef float f32x16 __attribute__((ext_vector_type(16)));
typedef float f32x4 __attribute__((ext_vector_type(4)));

// ---------------- fused prep: zero dw/counts + codebook norms + hi-fp16 pack ----------------
// wsB granule g (16B), fields LSB->MSB: l31(5) h(1) cfg(3) ks(2) dk(2) ct(2)  [g < 32768]
// content: fp16(hi) of cb[ct*256+cfg*32+l31][dk*64+ks*16+h*8+e], e=0..7
__global__ __launch_bounds__(256) void prep_kernel(const float* __restrict__ cb,
                                                   float* __restrict__ cnorm,
                                                   char* __restrict__ wsB,
                                                   float* __restrict__ dw,
                                                   float* __restrict__ counts) {
    const int tid = threadIdx.x;
    const int bid = blockIdx.x;
    const int g = bid * 256 + tid;          // 0..65535
    *reinterpret_cast<float4*>(dw + (size_t)g * 4) = make_float4(0.f, 0.f, 0.f, 0.f);
    if (g < K) counts[g] = 0.f;
    {
        const int row = bid * 4 + (tid >> 6);
        const int lane = tid & 63;
        const float4 v = *reinterpret_cast<const float4*>(cb + (size_t)row * D + lane * 4);
        float s = v.x * v.x + v.y * v.y + v.z * v.z + v.w * v.w;
        #pragma unroll
        for (int m = 32; m; m >>= 1) s += __shfl_xor(s, m);
        if (lane == 0) cnorm[row] = s;
    }
    if (g < 32768) {
        const int l31 = g & 31;
        const int h   = (g >> 5) & 1;
        const int cfg = (g >> 6) & 7;
        const int ks  = (g >> 9) & 3;
        const int dk  = (g >> 11) & 3;
        const int ct  = (g >> 13) & 3;
        const int code = ct * 256 + cfg * 32 + l31;
        const int dim0 = dk * 64 + ks * 16 + h * 8;
        const float* src = cb + (size_t)code * D + dim0;
        f16 out[8];
        #pragma unroll
        for (int e = 0; e < 8; ++e) out[e] = (f16)src[e];
        *reinterpret_cast<f16x8*>(wsB + (size_t)g * 16) = *reinterpret_cast<f16x8*>(out);
    }
}

// ---------------- coarse hi-fp16 argmin + candidate emission + exact fp32 refine ----------------
// block: 64 rows x 1024 codes, 256 thr = 4 waves (rw = wave>>1, cw = wave&1)
// wave tile per ct: 32 rows x 128 codes (4 cf of 32x32x16_f16, 1 MFMA each)
// LDS: A 8KB | B 32KB | cand u16[64][16] 2KB | ccnt int[64]
__global__ __launch_bounds__(256, 3) void argmin_coarse_kernel(
        const float* __restrict__ x, const float* __restrict__ cb,
        const char* __restrict__ wsB, const float* __restrict__ cnorm,
        int* __restrict__ idx_out, float* __restrict__ counts) {
    __shared__ char smem[43264];
    char* Alds = smem;                                   // 8192
    char* Blds = smem + 8192;                            // 32768
    unsigned short* cand = reinterpret_cast<unsigned short*>(smem + 40960);  // [64][16]
    int* ccnt = reinterpret_cast<int*>(smem + 43008);    // [64]
    const int tid = threadIdx.x;
    const int wave = tid >> 6;
    const int lane = tid & 63;
    const int l31 = lane & 31;
    const int h = lane >> 5;
    const int rw = wave >> 1;
    const int cw = wave & 1;
    const int n0 = blockIdx.x * 64;

    if (tid < 64) ccnt[tid] = 0;

    const int s_row = tid >> 2;          // 0..63
    const int c4 = tid & 3;              // 16-dim chunk
    const int ssw = s_row & 7;
    char* s_rowbase = Alds + s_row * 128;

    const int arow = rw * 32 + l31;
    const int asw = arow & 7;
    char* abase = Alds + arow * 128;

    float B_run[16];
    #pragma unroll
    for (int r = 0; r < 16; ++r) B_run[r] = 3.4e38f;

    #pragma unroll 1
    for (int ct = 0; ct < 4; ++ct) {
        f32x16 acc[4];
        #pragma unroll
        for (int cf = 0; cf < 4; ++cf)
            #pragma unroll
            for (int r = 0; r < 16; ++r) acc[cf][r] = 0.f;

        #pragma unroll 1
        for (int dks = 0; dks < 4; ++dks) {
            const int dk = (ct & 1) ? (3 - dks) : dks;   // serpentine A reuse
            __syncthreads();
            if (!(ct > 0 && dks == 0)) {
                // stage A: 64 rows x 64 dims -> hi fp16, swizzled 16B granules
                const float4 f0 = *reinterpret_cast<const float4*>(
                    x + (size_t)(n0 + s_row) * D + dk * 64 + c4 * 16);
                const float4 f1 = *reinterpret_cast<const float4*>(
                    x + (size_t)(n0 + s_row) * D + dk * 64 + c4 * 16 + 4);
                const float4 f2 = *reinterpret_cast<const float4*>(
                    x + (size_t)(n0 + s_row) * D + dk * 64 + c4 * 16 + 8);
                const float4 f3 = *reinterpret_cast<const float4*>(
                    x + (size_t)(n0 + s_row) * D + dk * 64 + c4 * 16 + 12);
                f16 hi8a[8] = {(f16)f0.x, (f16)f0.y, (f16)f0.z, (f16)f0.w,
                               (f16)f1.x, (f16)f1.y, (f16)f1.z, (f16)f1.w};
                f16 hi8b[8] = {(f16)f2.x, (f16)f2.y, (f16)f2.z, (f16)f2.w,
                               (f16)f3.x, (f16)f3.y, (f16)f3.z, (f16)f3.w};
                *reinterpret_cast<f16x8*>(s_rowbase + (((c4 * 2 + 0) ^ ssw) * 16)) = *reinterpret_cast<f16x8*>(hi8a);
                *reinterpret_cast<f16x8*>(s_rowbase + (((c4 * 2 + 1) ^ ssw) * 16)) = *reinterpret_cast<f16x8*>(hi8b);
            }
            // stage B: 32KB linear copy from pre-packed wsB
            {
                const int4* gsrc = reinterpret_cast<const int4*>(wsB + (size_t)(ct * 4 + dk) * 32768);
                int4* ldst = reinterpret_cast<int4*>(Blds);
                #pragma unroll
                for (int i = 0; i < 8; ++i) ldst[tid + i * 256] = gsrc[tid + i * 256];
            }
            __syncthreads();
            #pragma unroll
            for (int ks = 0; ks < 4; ++ks) {
                const int sA = ks * 2 + h;
                const f16x8 Ah = *reinterpret_cast<const f16x8*>(abase + ((sA ^ asw) * 16));
                #pragma unroll
                for (int cf = 0; cf < 4; ++cf) {
                    const f16x8 Bh = *reinterpret_cast<const f16x8*>(
                        Blds + (size_t)(ks * 8 + cw * 4 + cf) * 1024 + lane * 16);
                    acc[cf] = __builtin_amdgcn_mfma_f32_32x32x16_f16(Ah, Bh, acc[cf], 0, 0, 0);
                }
            }
        }
        // fold: per-row coarse min (butterfly over 32-lane halves) + margin emission
        const int codebase = ct * 256 + cw * 128;
        float cn[4];
        #pragma unroll
        for (int cf = 0; cf < 4; ++cf) cn[cf] = cnorm[codebase + cf * 32 + l31];
        #pragma unroll
        for (int r = 0; r < 16; ++r) {
            float d[4];
            float m = 3.4e38f;
            #pragma unroll
            for (int cf = 0; cf < 4; ++cf) {
                d[cf] = cn[cf] - 2.f * acc[cf][r];
                m = fminf(m, d[cf]);
            }
            #pragma unroll
            for (int msk = 16; msk; msk >>= 1) m = fminf(m, __shfl_xor(m, msk));
            const float br = fminf(B_run[r], m);
            B_run[r] = br;
            const float lim = br + MARGIN;
            const int row = rw * 32 + (r & 3) + 8 * (r >> 2) + 4 * h;
            #pragma unroll
            for (int cf = 0; cf < 4; ++cf) {
                if (d[cf] <= lim) {
                    const int pos = atomicAdd(&ccnt[row], 1);
                    if (pos < 16) cand[row * 16 + pos] = (unsigned short)(codebase + cf * 32 + l31);
                }
            }
        }
    }
    __syncthreads();
    // exact fp32 refine: wave w handles rows w*16..w*16+15
    #pragma unroll 1
    for (int rr = 0; rr < 16; ++rr) {
        const int row = wave * 16 + rr;
        const int n = ccnt[row];
        const f32x4 xv = *reinterpret_cast<const f32x4*>(x + (size_t)(n0 + row) * D + lane * 4);
        float bd = 3.4e38f;
        int bi = K;
        if (n <= 16) {
            for (int j = 0; j < n; ++j) {
                const int code = cand[row * 16 + j];
                const f32x4 cv = *reinterpret_cast<const f32x4*>(cb + (size_t)code * D + lane * 4);
                float s = xv[0] * cv[0] + xv[1] * cv[1] + xv[2] * cv[2] + xv[3] * cv[3];
                #pragma unroll
                for (int msk = 32; msk; msk >>= 1) s += __shfl_xor(s, msk);
                const float dd = cnorm[code] - 2.f * s;
                if (dd < bd || (dd == bd && code < bi)) { bd = dd; bi = code; }
            }
        } else {
            // overflow fallback: exact scan over all codes (correctness path, ~never taken)
            for (int code = 0; code < K; ++code) {
                const f32x4 cv = *reinterpret_cast<const f32x4*>(cb + (size_t)code * D + lane * 4);
                float s = xv[0] * cv[0] + xv[1] * cv[1] + xv[2] * cv[2] + xv[3] * cv[3];
                #pragma unroll
                for (int msk = 32; msk; msk >>= 1) s += __shfl_xor(s, msk);
                const float dd = cnorm[code] - 2.f * s;
                if (dd < bd) { bd = dd; bi = code; }
            }
        }
        if (lane == 0) {
            idx_out[n0 + row] = bi;
            atomicAdd(&counts[bi], 1.0f);
        }
    }
}

// ---------------- quantized gather (nontemporal stores) ----------------
__global__ __launch_bounds__(256) void quant_kernel(const float* __restrict__ cb,
                                                    const int* __restrict__ idx,
                                                    float* __restrict__ quant) {
    const int n = blockIdx.x * 4 + (threadIdx.x >> 6);
    const int lane = threadIdx.x & 63;
    const int i = idx[n];
    const f32x4 c = *reinterpret_cast<const f32x4*>(cb + (size_t)i * D + lane * 4);
    __builtin_nontemporal_store(c, reinterpret_cast<f32x4*>(quant + (size_t)n * D + lane * 4));
}

// ---------------- one-hot encodings (nontemporal stores) ----------------
__global__ __launch_bounds__(256) void enc_kernel(const int* __restrict__ idx,
                                                  float* __restrict__ enc) {
    const int total = N_ROWS * (K / 4);
    for (int g = blockIdx.x * blockDim.x + threadIdx.x; g < total;
         g += gridDim.x * blockDim.x) {
        const int n = g >> 8;
        const int k0 = (g & 255) * 4;
        const int i = idx[n];
        f32x4 v;
        v[0] = (k0 == i) ? 1.f : 0.f;
        v[1] = (k0 + 1 == i) ? 1.f : 0.f;
        v[2] = (k0 + 2 == i) ? 1.f : 0.f;
        v[3] = (k0 + 3 == i) ? 1.f : 0.f;
        __builtin_nontemporal_store(v, reinterpret_cast<f32x4*>(enc + (size_t)g * 4));
    }
}

// ---------------- cs EMA + Laplace + exclusive scan (wave-scan) ----------------
__global__ __launch_bounds__(1024) void cs_scan_kernel(const float* __restrict__ ema_cs,
                                                       const float* __restrict__ counts,
                                                       float* __restrict__ cs_out,
                                                       int* __restrict__ cursor) {
    __shared__ float wsum[16];
    __shared__ int wisum[16];
    __shared__ float n_sh;
    const int k = threadIdx.x;
    const int wid = k >> 6;
    const int lane = k & 63;
    const float cnt = counts[k];
    const float c = ema_cs[k] * DECAYF + OMDF * cnt;
    const int ic = (int)cnt;
    int v = ic;
    #pragma unroll
    for (int d = 1; d < 64; d <<= 1) {
        const int t = __shfl_up(v, d);
        if (lane >= d) v += t;
    }
    float s = c;
    #pragma unroll
    for (int m = 32; m; m >>= 1) s += __shfl_xor(s, m);
    if (lane == 63) wisum[wid] = v;
    if (lane == 0) wsum[wid] = s;
    __syncthreads();
    if (k == 0) {
        float n = 0.f;
        for (int w = 0; w < 16; ++w) n += wsum[w];
        n_sh = n;
    }
    if (wid == 0 && lane < 16) {
        int wv = wisum[lane];
        #pragma unroll
        for (int d = 1; d < 16; d <<= 1) {
            const int t = __shfl_up(wv, d);
            if (lane >= d) wv += t;
        }
        wisum[lane] = wv;
    }
    __syncthreads();
    const float n = n_sh;
    cs_out[k] = (c + EPSF) / (n + c * EPSF) * n;
    const int wbase = (wid == 0) ? 0 : wisum[wid - 1];
    cursor[k] = wbase + v - ic;
}

// ---------------- scatter rows by code, block-aggregated ----------------
__global__ __launch_bounds__(256) void scatter_kernel(const int* __restrict__ idx,
                                                      int* __restrict__ cursor,
                                                      int* __restrict__ rowlist,
                                                      int* __restrict__ codelist) {
    __shared__ int hist[1024];
    const int tid = threadIdx.x;
    #pragma unroll
    for (int j = 0; j < 4; ++j) hist[tid + j * 256] = 0;
    __syncthreads();
    const int n = blockIdx.x * 256 + tid;
    const int i = idx[n];
    atomicAdd(&hist[i], 1);
    __syncthreads();
    #pragma unroll
    for (int j = 0; j < 4; ++j) {
        const int k = tid + j * 256;
        const int c = hist[k];
        hist[k] = (c > 0) ? atomicAdd(&cursor[k], c) : 0;
    }
    __syncthreads();
    const int pos = atomicAdd(&hist[i], 1);
    rowlist[pos] = n;
    codelist[pos] = i;
}

// ---------------- balanced segmented sum over sorted rowlist ----------------
__global__ __launch_bounds__(256) void chunk_sum_kernel(const float* __restrict__ x,
                                                        const int* __restrict__ rowlist,
                                                        const int* __restrict__ codelist,
                                                        float* __restrict__ dw) {
    const int wave = threadIdx.x >> 6;
    const int lane = threadIdx.x & 63;
    const int p0 = blockIdx.x * 32 + wave * 8;
    int rows[8], codes[8];
    #pragma unroll
    for (int j = 0; j < 8; ++j) {
        rows[j] = rowlist[p0 + j];
        codes[j] = codelist[p0 + j];
    }
    f32x4 v[8];
    #pragma unroll
    for (int j = 0; j < 8; ++j)
        v[j] = __builtin_nontemporal_load(
            reinterpret_cast<const f32x4*>(x + (size_t)rows[j] * D + lane * 4));
    f32x4 s = v[0];
    int cur = codes[0];
    #pragma unroll
    for (int j = 1; j < 8; ++j) {
        if (codes[j] != cur) {
            float* dst = dw + (size_t)cur * D + lane * 4;
            atomicAdd(dst + 0, s[0]); atomicAdd(dst + 1, s[1]);
            atomicAdd(dst + 2, s[2]); atomicAdd(dst + 3, s[3]);
            cur = codes[j];
            s = v[j];
        } else {
            s[0] += v[j][0]; s[1] += v[j][1]; s[2] += v[j][2]; s[3] += v[j][3];
        }
    }
    float* dst = dw + (size_t)cur * D + lane * 4;
    atomicAdd(dst + 0, s[0]); atomicAdd(dst + 1, s[1]);
    atomicAdd(dst + 2, s[2]); atomicAdd(dst + 3, s[3]);
}

// ---------------- ema_w + new codebook ----------------
__global__ __launch_bounds__(256) void ema_kernel(const float* __restrict__ ema_w,
                                                  const float* __restrict__ dw,
                                                  const float* __restrict__ cs,
                                                  float* __restrict__ w_out,
                                                  float* __restrict__ cb_out) {
    const int e4 = blockIdx.x * blockDim.x + threadIdx.x;
    const int k = e4 >> 6;
    const float csk = cs[k];
    const float4 w = *reinterpret_cast<const float4*>(ema_w + (size_t)e4 * 4);
    const float4 d = *reinterpret_cast<const float4*>(dw + (size_t)e4 * 4);
    float4 nw, nc;
    nw.x = w.x * DECAYF + OMDF * d.x;
    nw.y = w.y * DECAYF + OMDF * d.y;
    nw.z = w.z * DECAYF + OMDF * d.z;
    nw.w = w.w * DECAYF + OMDF * d.w;
    nc.x = nw.x / csk; nc.y = nw.y / csk; nc.z = nw.z / csk; nc.w = nw.w / csk;
    *reinterpret_cast<float4*>(w_out + (size_t)e4 * 4) = nw;
    *reinterpret_cast<float4*>(cb_out + (size_t)e4 * 4) = nc;
}

extern "C" void kernel_launch(void* const* d_in, const int* in_sizes, int n_in,
                              void* d_out, int out_size, void* d_ws, size_t ws_size,
                              hipStream_t stream) {
    (void)in_sizes; (void)n_in; (void)out_size; (void)ws_size;
    const float* x      = (const float*)d_in[0];
    const float* cb     = (const float*)d_in[1];
    const float* ema_w  = (const float*)d_in[2];
    const float* ema_cs = (const float*)d_in[3];

    float* out    = (float*)d_out;
    float* quant  = out;
    float* enc    = quant + 16777216;
    float* cs_out = enc + 67108864;
    float* w_out  = cs_out + 1024;
    float* cb_out = w_out + 262144;

    float* ws       = (float*)d_ws;
    float* counts   = ws;                          // 1024 f
    float* dw       = ws + 1024;                   // 262144 f
    float* cnorm    = ws + 263168;                 // 1024 f
    int*   cursor   = (int*)(ws + 264192);         // 1024 i
    int*   idx      = (int*)(ws + 265216);         // 65536 i
    int*   rowlist  = (int*)(ws + 330752);         // 65536 i
    int*   codelist = (int*)(ws + 396288);         // 65536 i
    char*  wsB      = (char*)(ws + 461824);        // 512 KiB, 16B aligned

    prep_kernel<<<256, 256, 0, stream>>>(cb, cnorm, wsB, dw, counts);
    argmin_coarse_kernel<<<N_ROWS / 64, 256, 0, stream>>>(x, cb, wsB, cnorm, idx, counts);
    quant_kernel<<<N_ROWS / 4, 256, 0, stream>>>(cb, idx, quant);
    enc_kernel<<<2048, 256, 0, stream>>>(idx, enc);
    cs_scan_kernel<<<1, 1024, 0, stream>>>(ema_cs, counts, cs_out, cursor);
    scatter_kernel<<<N_ROWS / 256, 256, 0, stream>>>(idx, cursor, rowlist, codelist);
    chunk_sum_kernel<<<2048, 256, 0, stream>>>(x, rowlist, codelist, dw);
    ema_kernel<<<65536 / 256, 256, 0, stream>>>(ema_w, dw, cs_out, w_out, cb_out);
}